// Round 15
// baseline (242.855 us; speedup 1.0000x reference)
//
#include <hip/hip_runtime.h>
#include <hip/hip_fp16.h>
#include <math.h>

#define IN_FEATS 64
#define N_NODES 100000
#define N_EDGES 1600000
#define BSHIFT 7
#define NPB 128                              // nodes per bucket
#define NBUCK ((N_NODES + NPB - 1) / NPB)    // 782
#define CAP 4088                             // padded bucket capacity (mean 2046, sigma 45)
#define PCHUNK 8192
#define PGRID ((N_EDGES + PCHUNK - 1) / PCHUNK)  // 196

// sqrt(64 * log2(e)) : exp(-64 t^2) == exp2(-((K t))^2)
#define KSCALE 9.6089785f

// ---------------------------------------------------------------------------
// full edge coefficient (fallback path only)
// ---------------------------------------------------------------------------
__device__ __forceinline__ float edge_coef(float d, float mu) {
    float t = d - mu;
    float rbf = __expf(-64.0f * t * t);
    float x  = (d - 0.8f) * 5.0f;
    float xc = fminf(fmaxf(x, 0.0f), 1.0f);
    float ramp = 0.5f * (__cosf(3.14159265358979323846f * xc) + 1.0f);
    float fc = (d <= 0.8f) ? 1.0f : ((d >= 1.0f) ? 0.0f : ramp);
    return rbf * fc;
}

// lane-invariant smooth cutoff (computed once per edge, in partition)
__device__ __forceinline__ float cutoff_fc(float d) {
    float x  = (d - 0.8f) * 5.0f;
    float xc = fminf(fmaxf(x, 0.0f), 1.0f);
    float ramp = 0.5f * (__cosf(3.14159265358979323846f * xc) + 1.0f);
    return (d <= 0.8f) ? 1.0f : ((d >= 1.0f) ? 0.0f : ramp);
}

// ---------------------------------------------------------------------------
// Init: bcursor[b] = b*CAP, offs sentinel, W2 transpose into ws.
// ---------------------------------------------------------------------------
__global__ __launch_bounds__(256) void init_kernel(int* __restrict__ bcursor,
                                                   int* __restrict__ offs,
                                                   const float* __restrict__ W2,
                                                   float* __restrict__ W2T) {
    int i = blockIdx.x * 256 + threadIdx.x;
    if (i < NBUCK) bcursor[i] = i * CAP;
    if (i == 0) offs[N_NODES] = N_EDGES;   // sentinel
    if (i < 64 * 64) W2T[(i & 63) * 64 + (i >> 6)] = W2[i];
}

// ---------------------------------------------------------------------------
// Partition into padded bucket staging (d_out). Block-chunked reservation.
// Record: {src | (dst_local<<17),  (log2fc_f16 << 16) | d_unorm16}
// ---------------------------------------------------------------------------
__global__ __launch_bounds__(1024) void partition_kernel(const int* __restrict__ dst,
                                                         const int* __restrict__ src,
                                                         const float* __restrict__ dist,
                                                         int* __restrict__ bcursor,
                                                         int2* __restrict__ brec) {
    __shared__ int hist[NBUCK];
    __shared__ int base_[NBUCK];
    int tid = threadIdx.x;
    for (int i = tid; i < NBUCK; i += 1024) hist[i] = 0;
    __syncthreads();

    int e0 = blockIdx.x * PCHUNK;
    int e1 = min(e0 + PCHUNK, N_EDGES);

    for (int t = e0 + tid; t < e1; t += 1024)
        atomicAdd(&hist[dst[t] >> BSHIFT], 1);
    __syncthreads();

    for (int i = tid; i < NBUCK; i += 1024) {
        int hv = hist[i];
        if (hv) base_[i] = atomicAdd(&bcursor[i], hv);
        hist[i] = 0;      // reuse as local cursor
    }
    __syncthreads();

    for (int t = e0 + tid; t < e1; t += 1024) {
        int d  = dst[t];
        int b  = d >> BSHIFT;
        int r  = atomicAdd(&hist[b], 1);
        float dv = dist[t];
        float fc = cutoff_fc(dv);
        // log2(fc); fc==0 -> -512 (exp2(-512-t^2)==0)
        float lfc = (fc > 0.0f) ? __log2f(fc) : -512.0f;
        unsigned dq = (unsigned)(fminf(fmaxf(dv, 0.0f), 1.0f) * 65535.0f + 0.5f);
        unsigned hf = (unsigned)__half_as_ushort(__float2half(lfc));
        int2 rec;
        rec.x = src[t] | ((d & (NPB - 1)) << 17);
        rec.y = (int)((hf << 16) | dq);
        brec[(size_t)base_[b] + r] = rec;
    }
}

// ---------------------------------------------------------------------------
// Compact scan (post-partition): cnt[b] = bcursor[b]-b*CAP; boffs = excl scan.
// ---------------------------------------------------------------------------
__global__ __launch_bounds__(1024) void bscan_kernel(const int* __restrict__ bcursor,
                                                     int* __restrict__ boffs) {
    __shared__ int lds[1024];
    int tid = threadIdx.x;
    int v = (tid < NBUCK) ? (bcursor[tid] - tid * CAP) : 0;
    lds[tid] = v;
    __syncthreads();
    for (int off = 1; off < 1024; off <<= 1) {
        int x = (tid >= off) ? lds[tid - off] : 0;
        __syncthreads();
        lds[tid] += x;
        __syncthreads();
    }
    if (tid < NBUCK) boffs[tid] = lds[tid] - v;   // exclusive
    if (tid == 0) boffs[NBUCK] = N_EDGES;
}

// ---------------------------------------------------------------------------
// Node-sort: one block per bucket -> compact per-node CSR (rec_sorted, offs).
// ---------------------------------------------------------------------------
__global__ __launch_bounds__(256) void node_sort_kernel(const int2* __restrict__ brec,
                                                        const int* __restrict__ boffs,
                                                        int2* __restrict__ rec_sorted,
                                                        int* __restrict__ offs) {
    __shared__ int cntL[NPB];
    __shared__ int scanL[NPB];
    __shared__ int curL[NPB];

    int b   = blockIdx.x;
    int tid = threadIdx.x;
    int beg = boffs[b];
    int cnt = boffs[b + 1] - beg;
    size_t pbase = (size_t)b * CAP;
    int node0 = b << BSHIFT;

    for (int i = tid; i < NPB; i += 256) cntL[i] = 0;
    __syncthreads();

    for (int t = tid; t < cnt; t += 256)
        atomicAdd(&cntL[(brec[pbase + t].x >> 17) & (NPB - 1)], 1);
    __syncthreads();

    if (tid < NPB) scanL[tid] = cntL[tid];
    __syncthreads();
    for (int off = 1; off < NPB; off <<= 1) {
        int x = 0;
        if (tid < NPB && tid >= off) x = scanL[tid - off];
        __syncthreads();
        if (tid < NPB) scanL[tid] += x;
        __syncthreads();
    }
    if (tid < NPB) {
        int excl = scanL[tid] - cntL[tid];
        curL[tid] = excl;
        int node = node0 + tid;
        if (node < N_NODES) offs[node] = beg + excl;
    }
    __syncthreads();

    for (int t = tid; t < cnt; t += 256) {
        int2 r = brec[pbase + t];
        int dl = (r.x >> 17) & (NPB - 1);
        int p  = atomicAdd(&curL[dl], 1);
        rec_sorted[(size_t)beg + p] = r;
    }
}

// ---------------------------------------------------------------------------
// Aggregation: one wave per node, lane k owns feature k.
// Scalar record path (uniform addr -> s_load), coef = exp2(lfc - t^2).
// ---------------------------------------------------------------------------
__global__ __launch_bounds__(256) void agg_kernel(
    const float* __restrict__ h,
    const int* __restrict__ offs,
    const int2* __restrict__ rec_sorted,
    float* __restrict__ out)
{
    int w    = threadIdx.x >> 6;
    int lane = threadIdx.x & 63;
    int node = blockIdx.x * 4 + w;
    if (node >= N_NODES) return;

    int beg = __builtin_amdgcn_readfirstlane(offs[node]);
    int end = __builtin_amdgcn_readfirstlane(offs[node + 1]);
    float muK = (float)lane * (KSCALE / 63.0f);
    float acc0 = 0.0f, acc1 = 0.0f;

#define REC(J, ACC) { \
        int2 r_ = rec_sorted[(size_t)(J)]; \
        int rx_ = __builtin_amdgcn_readfirstlane(r_.x); \
        unsigned ry_ = (unsigned)__builtin_amdgcn_readfirstlane(r_.y); \
        float hv_ = h[((size_t)(rx_ & 0x1FFFF) << 6) + lane]; \
        float dqf_ = (float)(ry_ & 0xFFFFu); \
        float lfc_ = __half2float(__ushort_as_half((unsigned short)(ry_ >> 16))); \
        float t_  = fmaf(dqf_, (KSCALE / 65535.0f), -muK); \
        float a_  = fmaf(-t_, t_, lfc_); \
        ACC = fmaf(hv_, exp2f(a_), ACC); }

    int i = beg;
    int main_end = beg + ((end - beg) & ~7);
    for (; i < main_end; i += 8) {
        REC(i + 0, acc0) REC(i + 1, acc1) REC(i + 2, acc0) REC(i + 3, acc1)
        REC(i + 4, acc0) REC(i + 5, acc1) REC(i + 6, acc0) REC(i + 7, acc1)
    }
    for (; i < end; ++i) { REC(i, acc0) }
#undef REC

    out[(size_t)node * 64 + lane] = acc0 + acc1;
}

// ---------------------------------------------------------------------------
// MLP v4: lane = node, j-SPLIT ACROSS 4 WAVES (16 output feats each).
// 1024-thr block = 4 node-groups x 4 splits; grid 391 -> 6256 waves (4x).
// acc[16] (low VGPR), W via scalar loads, hid exchanged through padded LDS
// at the softplus boundary. 64B-aligned 16-float output chunks per lane.
// ---------------------------------------------------------------------------
__global__ __launch_bounds__(1024, 1) void mlp_kernel(
    float* __restrict__ io,
    const float* __restrict__ W1, const float* __restrict__ b1,
    const float* __restrict__ W2T, const float* __restrict__ b2)
{
    __shared__ float sHid[4][64][65];   // 66.56 KB, +1 pad -> conflict-free

    int tid  = threadIdx.x;
    int lane = tid & 63;
    int wid  = tid >> 6;         // 0..15
    int g    = wid >> 2;         // node-group 0..3
    int s    = wid & 3;          // j-split 0..3
    int j0   = s * 16;
    int node = blockIdx.x * 256 + g * 64 + lane;
    bool valid = node < N_NODES;
    int nclamp = valid ? node : (N_NODES - 1);

    const float4* rowp = (const float4*)(io + (size_t)nclamp * 64);
    float4 rv[16];
    #pragma unroll
    for (int kc = 0; kc < 16; ++kc) rv[kc] = rowp[kc];

    float acc[16];
    #pragma unroll
    for (int j = 0; j < 16; ++j) acc[j] = b1[j0 + j];

    #pragma unroll
    for (int kc = 0; kc < 16; ++kc) {
        const float* wr = W1 + kc * 256 + j0;
        #pragma unroll
        for (int j = 0; j < 16; ++j) acc[j] = fmaf(rv[kc].x, wr[j], acc[j]);
        #pragma unroll
        for (int j = 0; j < 16; ++j) acc[j] = fmaf(rv[kc].y, wr[64 + j], acc[j]);
        #pragma unroll
        for (int j = 0; j < 16; ++j) acc[j] = fmaf(rv[kc].z, wr[128 + j], acc[j]);
        #pragma unroll
        for (int j = 0; j < 16; ++j) acc[j] = fmaf(rv[kc].w, wr[192 + j], acc[j]);
    }

    // softplus + publish hid slice to LDS
    #pragma unroll
    for (int j = 0; j < 16; ++j) {
        float v = acc[j];
        float e = exp2f(v * 1.44269504089f);
        float sp = 0.69314718056f * __log2f(1.0f + e);
        float hv = (v > 20.0f) ? v : sp;
        sHid[g][lane][j0 + j] = hv;
    }
    __syncthreads();

    // layer 2: o[j] = b2 + sum_k hid[k] * W2T[j][k]
    float o[16];
    #pragma unroll
    for (int j = 0; j < 16; ++j) o[j] = b2[j0 + j];

    for (int k = 0; k < 64; k += 4) {
        float h0 = sHid[g][lane][k];
        float h1 = sHid[g][lane][k + 1];
        float h2 = sHid[g][lane][k + 2];
        float h3 = sHid[g][lane][k + 3];
        #pragma unroll
        for (int j = 0; j < 16; ++j) {
            const float* wr = W2T + (j0 + j) * 64 + k;
            float t0 = fmaf(h0, wr[0], fmaf(h1, wr[1], 0.f));
            float t1 = fmaf(h2, wr[2], fmaf(h3, wr[3], 0.f));
            o[j] += t0 + t1;
        }
    }

    if (valid) {
        float4* op = (float4*)(io + (size_t)node * 64 + j0);
        op[0] = make_float4(o[0],  o[1],  o[2],  o[3]);
        op[1] = make_float4(o[4],  o[5],  o[6],  o[7]);
        op[2] = make_float4(o[8],  o[9],  o[10], o[11]);
        op[3] = make_float4(o[12], o[13], o[14], o[15]);
    }
}

// ---------------------------------------------------------------------------
// Fallback (ws too small): atomic scatter-add path + simple MLP.
// ---------------------------------------------------------------------------
__global__ __launch_bounds__(256) void schnet_edge_kernel(
    const float* __restrict__ h,
    const float* __restrict__ dist,
    const int* __restrict__ src_idx,
    const int* __restrict__ dst_idx,
    float* __restrict__ agg)
{
    long long idx = (long long)blockIdx.x * 256 + threadIdx.x;
    int e = (int)(idx >> 6);
    if (e >= N_EDGES) return;
    int k = (int)(idx & 63);
    float d = dist[e];
    float c = edge_coef(d, (float)k * (1.0f / 63.0f));
    int s  = src_idx[e];
    int dn = dst_idx[e];
    atomicAdd(&agg[(long long)dn * 64 + k], h[(long long)s * 64 + k] * c);
}

__global__ __launch_bounds__(256) void mlp_fallback_kernel(
    float* __restrict__ io,
    const float* __restrict__ W1, const float* __restrict__ b1,
    const float* __restrict__ W2, const float* __restrict__ b2)
{
    __shared__ float sW1[64 * 64];
    __shared__ float sW2[64 * 64];
    __shared__ float sRow[4][64];
    __shared__ float sHid[4][64];
    int tid = threadIdx.x;
    for (int i = tid; i < 4096; i += 256) { sW1[i] = W1[i]; sW2[i] = W2[i]; }
    __syncthreads();
    int lane = tid & 63, w = tid >> 6;
    float bb1 = b1[lane], bb2 = b2[lane];
    for (int base = blockIdx.x * 4; base < N_NODES; base += gridDim.x * 4) {
        int node = base + w;
        if (node < N_NODES) sRow[w][lane] = io[(size_t)node * 64 + lane];
        __syncthreads();
        float a = bb1;
        #pragma unroll
        for (int k = 0; k < 64; ++k) a = fmaf(sRow[w][k], sW1[k * 64 + lane], a);
        sHid[w][lane] = (a > 20.f) ? a : log1pf(__expf(a));
        __syncthreads();
        float c = bb2;
        #pragma unroll
        for (int k = 0; k < 64; ++k) c = fmaf(sHid[w][k], sW2[k * 64 + lane], c);
        if (node < N_NODES) io[(size_t)node * 64 + lane] = c;
        __syncthreads();
    }
}

extern "C" void kernel_launch(void* const* d_in, const int* in_sizes, int n_in,
                              void* d_out, int out_size, void* d_ws, size_t ws_size,
                              hipStream_t stream) {
    const float* h    = (const float*)d_in[0];
    const float* dist = (const float*)d_in[1];
    const float* W1   = (const float*)d_in[2];
    const float* b1   = (const float*)d_in[3];
    const float* W2   = (const float*)d_in[4];
    const float* b2   = (const float*)d_in[5];
    const int* src    = (const int*)d_in[6];
    const int* dst    = (const int*)d_in[7];
    float* out        = (float*)d_out;

    // ws layout (ints): rec_sorted[2E] | boffs[NBUCK+1] | bcursor[NBUCK] |
    //                   offs[N+1] | W2T[4096 floats]
    size_t needed = ((size_t)2 * N_EDGES + NBUCK + 1 + NBUCK + N_NODES + 1 + 4096)
                    * sizeof(int);

    if (ws_size >= needed) {
        int2* rec_sorted = (int2*)d_ws;
        int* boffs       = (int*)d_ws + (size_t)2 * N_EDGES;   // NBUCK+1
        int* bcursor     = boffs + NBUCK + 1;
        int* offs        = bcursor + NBUCK;                    // N+1
        float* W2T       = (float*)(offs + N_NODES + 1);       // 4096

        // padded bucket staging in d_out (782*4088 recs = 25.57MB <= 25.6MB)
        int2* brec = (int2*)d_out;

        init_kernel<<<16, 256, 0, stream>>>(bcursor, offs, W2, W2T);
        partition_kernel<<<PGRID, 1024, 0, stream>>>(dst, src, dist, bcursor, brec);
        bscan_kernel<<<1, 1024, 0, stream>>>(bcursor, boffs);
        node_sort_kernel<<<NBUCK, 256, 0, stream>>>(brec, boffs, rec_sorted, offs);
        agg_kernel<<<N_NODES / 4, 256, 0, stream>>>(h, offs, rec_sorted, out);
        mlp_kernel<<<(N_NODES + 255) / 256, 1024, 0, stream>>>(out, W1, b1, W2T, b2);
    } else {
        hipMemsetAsync(out, 0, (size_t)N_NODES * IN_FEATS * sizeof(float), stream);
        long long total = (long long)N_EDGES * 64;
        schnet_edge_kernel<<<(int)((total + 255) / 256), 256, 0, stream>>>(
            h, dist, src, dst, out);
        mlp_fallback_kernel<<<2048, 256, 0, stream>>>(out, W1, b1, W2, b2);
    }
}

// Round 16
// 168.949 us; speedup vs baseline: 1.4374x; 1.4374x over previous
//
#include <hip/hip_runtime.h>
#include <hip/hip_fp16.h>
#include <math.h>

#define IN_FEATS 64
#define N_NODES 100000
#define N_EDGES 1600000
#define BSHIFT 7
#define NPB 128                              // nodes per bucket
#define NBUCK ((N_NODES + NPB - 1) / NPB)    // 782
#define CAP 4088                             // padded bucket capacity (mean 2046, sigma 45)
#define PCHUNK 8192
#define PGRID ((N_EDGES + PCHUNK - 1) / PCHUNK)  // 196

// sqrt(64 * log2(e)) : exp(-64 t^2) == exp2(-((K t))^2)
#define KSCALE 9.6089785f

// ---------------------------------------------------------------------------
// full edge coefficient (fallback path only)
// ---------------------------------------------------------------------------
__device__ __forceinline__ float edge_coef(float d, float mu) {
    float t = d - mu;
    float rbf = __expf(-64.0f * t * t);
    float x  = (d - 0.8f) * 5.0f;
    float xc = fminf(fmaxf(x, 0.0f), 1.0f);
    float ramp = 0.5f * (__cosf(3.14159265358979323846f * xc) + 1.0f);
    float fc = (d <= 0.8f) ? 1.0f : ((d >= 1.0f) ? 0.0f : ramp);
    return rbf * fc;
}

// lane-invariant smooth cutoff (computed once per edge, in partition)
__device__ __forceinline__ float cutoff_fc(float d) {
    float x  = (d - 0.8f) * 5.0f;
    float xc = fminf(fmaxf(x, 0.0f), 1.0f);
    float ramp = 0.5f * (__cosf(3.14159265358979323846f * xc) + 1.0f);
    return (d <= 0.8f) ? 1.0f : ((d >= 1.0f) ? 0.0f : ramp);
}

// ---------------------------------------------------------------------------
// Init: bcursor[b] = b*CAP, offs sentinel, W2 transpose into ws.
// ---------------------------------------------------------------------------
__global__ __launch_bounds__(256) void init_kernel(int* __restrict__ bcursor,
                                                   int* __restrict__ offs,
                                                   const float* __restrict__ W2,
                                                   float* __restrict__ W2T) {
    int i = blockIdx.x * 256 + threadIdx.x;
    if (i < NBUCK) bcursor[i] = i * CAP;
    if (i == 0) offs[N_NODES] = N_EDGES;   // sentinel
    if (i < 64 * 64) W2T[(i & 63) * 64 + (i >> 6)] = W2[i];
}

// ---------------------------------------------------------------------------
// Partition into padded bucket staging (d_out). Block-chunked reservation.
// Record: {src | (dst_local<<17),  (log2fc_f16 << 16) | d_unorm16}
// ---------------------------------------------------------------------------
__global__ __launch_bounds__(1024) void partition_kernel(const int* __restrict__ dst,
                                                         const int* __restrict__ src,
                                                         const float* __restrict__ dist,
                                                         int* __restrict__ bcursor,
                                                         int2* __restrict__ brec) {
    __shared__ int hist[NBUCK];
    __shared__ int base_[NBUCK];
    int tid = threadIdx.x;
    for (int i = tid; i < NBUCK; i += 1024) hist[i] = 0;
    __syncthreads();

    int e0 = blockIdx.x * PCHUNK;
    int e1 = min(e0 + PCHUNK, N_EDGES);

    for (int t = e0 + tid; t < e1; t += 1024)
        atomicAdd(&hist[dst[t] >> BSHIFT], 1);
    __syncthreads();

    for (int i = tid; i < NBUCK; i += 1024) {
        int hv = hist[i];
        if (hv) base_[i] = atomicAdd(&bcursor[i], hv);
        hist[i] = 0;      // reuse as local cursor
    }
    __syncthreads();

    for (int t = e0 + tid; t < e1; t += 1024) {
        int d  = dst[t];
        int b  = d >> BSHIFT;
        int r  = atomicAdd(&hist[b], 1);
        float dv = dist[t];
        float fc = cutoff_fc(dv);
        // log2(fc); fc==0 -> -512 (exp2(-512-t^2)==0)
        float lfc = (fc > 0.0f) ? __log2f(fc) : -512.0f;
        unsigned dq = (unsigned)(fminf(fmaxf(dv, 0.0f), 1.0f) * 65535.0f + 0.5f);
        unsigned hf = (unsigned)__half_as_ushort(__float2half(lfc));
        int2 rec;
        rec.x = src[t] | ((d & (NPB - 1)) << 17);
        rec.y = (int)((hf << 16) | dq);
        brec[(size_t)base_[b] + r] = rec;
    }
}

// ---------------------------------------------------------------------------
// Compact scan (post-partition): cnt[b] = bcursor[b]-b*CAP; boffs = excl scan.
// ---------------------------------------------------------------------------
__global__ __launch_bounds__(1024) void bscan_kernel(const int* __restrict__ bcursor,
                                                     int* __restrict__ boffs) {
    __shared__ int lds[1024];
    int tid = threadIdx.x;
    int v = (tid < NBUCK) ? (bcursor[tid] - tid * CAP) : 0;
    lds[tid] = v;
    __syncthreads();
    for (int off = 1; off < 1024; off <<= 1) {
        int x = (tid >= off) ? lds[tid - off] : 0;
        __syncthreads();
        lds[tid] += x;
        __syncthreads();
    }
    if (tid < NBUCK) boffs[tid] = lds[tid] - v;   // exclusive
    if (tid == 0) boffs[NBUCK] = N_EDGES;
}

// ---------------------------------------------------------------------------
// Node-sort: one block per bucket -> compact per-node CSR (rec_sorted, offs).
// ---------------------------------------------------------------------------
__global__ __launch_bounds__(256) void node_sort_kernel(const int2* __restrict__ brec,
                                                        const int* __restrict__ boffs,
                                                        int2* __restrict__ rec_sorted,
                                                        int* __restrict__ offs) {
    __shared__ int cntL[NPB];
    __shared__ int scanL[NPB];
    __shared__ int curL[NPB];

    int b   = blockIdx.x;
    int tid = threadIdx.x;
    int beg = boffs[b];
    int cnt = boffs[b + 1] - beg;
    size_t pbase = (size_t)b * CAP;
    int node0 = b << BSHIFT;

    for (int i = tid; i < NPB; i += 256) cntL[i] = 0;
    __syncthreads();

    for (int t = tid; t < cnt; t += 256)
        atomicAdd(&cntL[(brec[pbase + t].x >> 17) & (NPB - 1)], 1);
    __syncthreads();

    if (tid < NPB) scanL[tid] = cntL[tid];
    __syncthreads();
    for (int off = 1; off < NPB; off <<= 1) {
        int x = 0;
        if (tid < NPB && tid >= off) x = scanL[tid - off];
        __syncthreads();
        if (tid < NPB) scanL[tid] += x;
        __syncthreads();
    }
    if (tid < NPB) {
        int excl = scanL[tid] - cntL[tid];
        curL[tid] = excl;
        int node = node0 + tid;
        if (node < N_NODES) offs[node] = beg + excl;
    }
    __syncthreads();

    for (int t = tid; t < cnt; t += 256) {
        int2 r = brec[pbase + t];
        int dl = (r.x >> 17) & (NPB - 1);
        int p  = atomicAdd(&curL[dl], 1);
        rec_sorted[(size_t)beg + p] = r;
    }
}

// ---------------------------------------------------------------------------
// Aggregation: one wave per node, lane k owns feature k.
// Scalar record path (uniform addr -> s_load), coef = exp2(lfc - t^2).
// ---------------------------------------------------------------------------
__global__ __launch_bounds__(256) void agg_kernel(
    const float* __restrict__ h,
    const int* __restrict__ offs,
    const int2* __restrict__ rec_sorted,
    float* __restrict__ out)
{
    int w    = threadIdx.x >> 6;
    int lane = threadIdx.x & 63;
    int node = blockIdx.x * 4 + w;
    if (node >= N_NODES) return;

    int beg = __builtin_amdgcn_readfirstlane(offs[node]);
    int end = __builtin_amdgcn_readfirstlane(offs[node + 1]);
    float muK = (float)lane * (KSCALE / 63.0f);
    float acc0 = 0.0f, acc1 = 0.0f;

#define REC(J, ACC) { \
        int2 r_ = rec_sorted[(size_t)(J)]; \
        int rx_ = __builtin_amdgcn_readfirstlane(r_.x); \
        unsigned ry_ = (unsigned)__builtin_amdgcn_readfirstlane(r_.y); \
        float hv_ = h[((size_t)(rx_ & 0x1FFFF) << 6) + lane]; \
        float dqf_ = (float)(ry_ & 0xFFFFu); \
        float lfc_ = __half2float(__ushort_as_half((unsigned short)(ry_ >> 16))); \
        float t_  = fmaf(dqf_, (KSCALE / 65535.0f), -muK); \
        float a_  = fmaf(-t_, t_, lfc_); \
        ACC = fmaf(hv_, exp2f(a_), ACC); }

    int i = beg;
    int main_end = beg + ((end - beg) & ~7);
    for (; i < main_end; i += 8) {
        REC(i + 0, acc0) REC(i + 1, acc1) REC(i + 2, acc0) REC(i + 3, acc1)
        REC(i + 4, acc0) REC(i + 5, acc1) REC(i + 6, acc0) REC(i + 7, acc1)
    }
    for (; i < end; ++i) { REC(i, acc0) }
#undef REC

    out[(size_t)node * 64 + lane] = acc0 + acc1;
}

// ---------------------------------------------------------------------------
// MLP v5: lane = node; W1/W2T staged in LDS (32KB), read via same-address
// ds_read_b128 (hardware broadcast, conflict-free, ~120cy latency) — no
// scalar-L1-thrashing s_load chains. Dynamic outer loops keep code small;
// all acc[]/o[] indices compile-time static (no scratch).
// ---------------------------------------------------------------------------
__global__ __launch_bounds__(256, 1) void mlp_kernel(
    float* __restrict__ io,
    const float* __restrict__ W1, const float* __restrict__ b1,
    const float* __restrict__ W2T, const float* __restrict__ b2)
{
    __shared__ float sW1[4096];
    __shared__ float sW2T[4096];

    int tid = threadIdx.x;
    for (int i = tid; i < 1024; i += 256) {
        ((float4*)sW1)[i]  = ((const float4*)W1)[i];
        ((float4*)sW2T)[i] = ((const float4*)W2T)[i];
    }
    __syncthreads();

    int lane = tid & 63;
    int wv   = tid >> 6;
    int node = (blockIdx.x * 4 + wv) * 64 + lane;
    bool valid = node < N_NODES;
    int nclamp = valid ? node : (N_NODES - 1);
    const float4* rowp = (const float4*)(io + (size_t)nclamp * 64);

    float acc[64];
    #pragma unroll
    for (int j = 0; j < 64; ++j) acc[j] = b1[j];

    // layer 1: acc[j] += row[k] * W1[k][j]
    for (int kc = 0; kc < 16; ++kc) {          // dynamic: small code
        float4 rv = rowp[kc];
        #pragma unroll
        for (int ku = 0; ku < 4; ++ku) {
            float rk = (ku == 0) ? rv.x : (ku == 1) ? rv.y : (ku == 2) ? rv.z : rv.w;
            const float* wr = sW1 + (kc * 4 + ku) * 64;
            #pragma unroll
            for (int jc = 0; jc < 16; ++jc) {
                float4 wv4 = *(const float4*)(wr + jc * 4);   // broadcast ds_read_b128
                acc[jc * 4 + 0] = fmaf(rk, wv4.x, acc[jc * 4 + 0]);
                acc[jc * 4 + 1] = fmaf(rk, wv4.y, acc[jc * 4 + 1]);
                acc[jc * 4 + 2] = fmaf(rk, wv4.z, acc[jc * 4 + 2]);
                acc[jc * 4 + 3] = fmaf(rk, wv4.w, acc[jc * 4 + 3]);
            }
        }
    }

    // softplus: log(1+e^x) = log2(1+2^(x*log2e)) * ln2
    #pragma unroll
    for (int j = 0; j < 64; ++j) {
        float v = acc[j];
        float e = exp2f(v * 1.44269504089f);
        float sp = 0.69314718056f * __log2f(1.0f + e);
        acc[j] = (v > 20.0f) ? v : sp;
    }

    // layer 2: o[j] = b2[j] + sum_k hid[k] * W2T[j][k]; 16 feats per jb pass,
    // stores grouped 64B-per-line.
    float* orow = io + (size_t)node * 64;
    for (int jb = 0; jb < 4; ++jb) {           // dynamic
        float o[16];
        #pragma unroll
        for (int ju = 0; ju < 16; ++ju) o[ju] = b2[jb * 16 + ju];
        #pragma unroll
        for (int ju = 0; ju < 16; ++ju) {
            const float* wr = sW2T + (jb * 16 + ju) * 64;
            float s0 = 0.f, s1 = 0.f, s2 = 0.f, s3 = 0.f;
            #pragma unroll
            for (int k = 0; k < 64; k += 16) {
                float4 a = *(const float4*)(wr + k);
                float4 b = *(const float4*)(wr + k + 4);
                float4 c = *(const float4*)(wr + k + 8);
                float4 d = *(const float4*)(wr + k + 12);
                s0 = fmaf(acc[k + 0], a.x, fmaf(acc[k + 1], a.y,
                     fmaf(acc[k + 2], a.z, fmaf(acc[k + 3], a.w, s0))));
                s1 = fmaf(acc[k + 4], b.x, fmaf(acc[k + 5], b.y,
                     fmaf(acc[k + 6], b.z, fmaf(acc[k + 7], b.w, s1))));
                s2 = fmaf(acc[k + 8], c.x, fmaf(acc[k + 9], c.y,
                     fmaf(acc[k + 10], c.z, fmaf(acc[k + 11], c.w, s2))));
                s3 = fmaf(acc[k + 12], d.x, fmaf(acc[k + 13], d.y,
                     fmaf(acc[k + 14], d.z, fmaf(acc[k + 15], d.w, s3))));
            }
            o[ju] += (s0 + s1) + (s2 + s3);
        }
        if (valid) {
            float4* op = (float4*)(orow + jb * 16);
            op[0] = make_float4(o[0],  o[1],  o[2],  o[3]);
            op[1] = make_float4(o[4],  o[5],  o[6],  o[7]);
            op[2] = make_float4(o[8],  o[9],  o[10], o[11]);
            op[3] = make_float4(o[12], o[13], o[14], o[15]);
        }
    }
}

// ---------------------------------------------------------------------------
// Fallback (ws too small): atomic scatter-add path + simple MLP.
// ---------------------------------------------------------------------------
__global__ __launch_bounds__(256) void schnet_edge_kernel(
    const float* __restrict__ h,
    const float* __restrict__ dist,
    const int* __restrict__ src_idx,
    const int* __restrict__ dst_idx,
    float* __restrict__ agg)
{
    long long idx = (long long)blockIdx.x * 256 + threadIdx.x;
    int e = (int)(idx >> 6);
    if (e >= N_EDGES) return;
    int k = (int)(idx & 63);
    float d = dist[e];
    float c = edge_coef(d, (float)k * (1.0f / 63.0f));
    int s  = src_idx[e];
    int dn = dst_idx[e];
    atomicAdd(&agg[(long long)dn * 64 + k], h[(long long)s * 64 + k] * c);
}

__global__ __launch_bounds__(256) void mlp_fallback_kernel(
    float* __restrict__ io,
    const float* __restrict__ W1, const float* __restrict__ b1,
    const float* __restrict__ W2, const float* __restrict__ b2)
{
    __shared__ float sW1[64 * 64];
    __shared__ float sW2[64 * 64];
    __shared__ float sRow[4][64];
    __shared__ float sHid[4][64];
    int tid = threadIdx.x;
    for (int i = tid; i < 4096; i += 256) { sW1[i] = W1[i]; sW2[i] = W2[i]; }
    __syncthreads();
    int lane = tid & 63, w = tid >> 6;
    float bb1 = b1[lane], bb2 = b2[lane];
    for (int base = blockIdx.x * 4; base < N_NODES; base += gridDim.x * 4) {
        int node = base + w;
        if (node < N_NODES) sRow[w][lane] = io[(size_t)node * 64 + lane];
        __syncthreads();
        float a = bb1;
        #pragma unroll
        for (int k = 0; k < 64; ++k) a = fmaf(sRow[w][k], sW1[k * 64 + lane], a);
        sHid[w][lane] = (a > 20.f) ? a : log1pf(__expf(a));
        __syncthreads();
        float c = bb2;
        #pragma unroll
        for (int k = 0; k < 64; ++k) c = fmaf(sHid[w][k], sW2[k * 64 + lane], c);
        if (node < N_NODES) io[(size_t)node * 64 + lane] = c;
        __syncthreads();
    }
}

extern "C" void kernel_launch(void* const* d_in, const int* in_sizes, int n_in,
                              void* d_out, int out_size, void* d_ws, size_t ws_size,
                              hipStream_t stream) {
    const float* h    = (const float*)d_in[0];
    const float* dist = (const float*)d_in[1];
    const float* W1   = (const float*)d_in[2];
    const float* b1   = (const float*)d_in[3];
    const float* W2   = (const float*)d_in[4];
    const float* b2   = (const float*)d_in[5];
    const int* src    = (const int*)d_in[6];
    const int* dst    = (const int*)d_in[7];
    float* out        = (float*)d_out;

    // ws layout (ints): rec_sorted[2E] | boffs[NBUCK+1] | bcursor[NBUCK] |
    //                   offs[N+1] | W2T[4096 floats]
    size_t needed = ((size_t)2 * N_EDGES + NBUCK + 1 + NBUCK + N_NODES + 1 + 4096)
                    * sizeof(int);

    if (ws_size >= needed) {
        int2* rec_sorted = (int2*)d_ws;
        int* boffs       = (int*)d_ws + (size_t)2 * N_EDGES;   // NBUCK+1
        int* bcursor     = boffs + NBUCK + 1;
        int* offs        = bcursor + NBUCK;                    // N+1
        float* W2T       = (float*)(offs + N_NODES + 1);       // 4096

        // padded bucket staging in d_out (782*4088 recs = 25.57MB <= 25.6MB)
        int2* brec = (int2*)d_out;

        init_kernel<<<16, 256, 0, stream>>>(bcursor, offs, W2, W2T);
        partition_kernel<<<PGRID, 1024, 0, stream>>>(dst, src, dist, bcursor, brec);
        bscan_kernel<<<1, 1024, 0, stream>>>(bcursor, boffs);
        node_sort_kernel<<<NBUCK, 256, 0, stream>>>(brec, boffs, rec_sorted, offs);
        agg_kernel<<<N_NODES / 4, 256, 0, stream>>>(h, offs, rec_sorted, out);
        mlp_kernel<<<(N_NODES + 255) / 256, 256, 0, stream>>>(out, W1, b1, W2T, b2);
    } else {
        hipMemsetAsync(out, 0, (size_t)N_NODES * IN_FEATS * sizeof(float), stream);
        long long total = (long long)N_EDGES * 64;
        schnet_edge_kernel<<<(int)((total + 255) / 256), 256, 0, stream>>>(
            h, dist, src, dst, out);
        mlp_fallback_kernel<<<2048, 256, 0, stream>>>(out, W1, b1, W2, b2);
    }
}

// Round 17
// 124.378 us; speedup vs baseline: 1.9526x; 1.3583x over previous
//
#include <hip/hip_runtime.h>
#include <hip/hip_fp16.h>
#include <math.h>

#define IN_FEATS 64
#define N_NODES 100000
#define N_EDGES 1600000
#define BSHIFT 7
#define NPB 128                              // nodes per bucket
#define NBUCK ((N_NODES + NPB - 1) / NPB)    // 782
#define CAP 4088                             // padded bucket capacity (mean 2046, sigma 45)
#define PCHUNK 8192
#define PGRID ((N_EDGES + PCHUNK - 1) / PCHUNK)  // 196
#define NGRP (N_NODES / 16)                  // 6250 (exact)

// sqrt(64 * log2(e)) : exp(-64 t^2) == exp2(-((K t))^2)
#define KSCALE 9.6089785f

typedef __attribute__((ext_vector_type(8))) short short8_t;
typedef __attribute__((ext_vector_type(4))) float f32x4_t;

#define MFMA16(a, b, c) __builtin_amdgcn_mfma_f32_16x16x32_bf16(a, b, c, 0, 0, 0)

__device__ __forceinline__ unsigned short bf16_rne(float x) {
    unsigned u = __float_as_uint(x);
    unsigned r = u + 0x7FFFu + ((u >> 16) & 1u);
    return (unsigned short)(r >> 16);
}

__device__ __forceinline__ short8_t u4_to_s8(uint4 v) {
    union { uint4 u; short8_t s; } cv; cv.u = v; return cv.s;
}

// split 8 f32 (two float4) into hi/lo bf16 fragments
__device__ __forceinline__ void split8(float4 a, float4 b,
                                       short8_t* hi, short8_t* lo) {
    float x0 = a.x, x1 = a.y, x2 = a.z, x3 = a.w;
    float x4 = b.x, x5 = b.y, x6 = b.z, x7 = b.w;
    short8_t h, l;
#define SP(I, X) { unsigned short hu = bf16_rne(X); \
        float hf = __uint_as_float((unsigned)hu << 16); \
        unsigned short lu = bf16_rne((X) - hf); \
        h[I] = (short)hu; l[I] = (short)lu; }
    SP(0, x0) SP(1, x1) SP(2, x2) SP(3, x3)
    SP(4, x4) SP(5, x5) SP(6, x6) SP(7, x7)
#undef SP
    *hi = h; *lo = l;
}

// ---------------------------------------------------------------------------
// full edge coefficient (fallback path only)
// ---------------------------------------------------------------------------
__device__ __forceinline__ float edge_coef(float d, float mu) {
    float t = d - mu;
    float rbf = __expf(-64.0f * t * t);
    float x  = (d - 0.8f) * 5.0f;
    float xc = fminf(fmaxf(x, 0.0f), 1.0f);
    float ramp = 0.5f * (__cosf(3.14159265358979323846f * xc) + 1.0f);
    float fc = (d <= 0.8f) ? 1.0f : ((d >= 1.0f) ? 0.0f : ramp);
    return rbf * fc;
}

__device__ __forceinline__ float cutoff_fc(float d) {
    float x  = (d - 0.8f) * 5.0f;
    float xc = fminf(fmaxf(x, 0.0f), 1.0f);
    float ramp = 0.5f * (__cosf(3.14159265358979323846f * xc) + 1.0f);
    return (d <= 0.8f) ? 1.0f : ((d >= 1.0f) ? 0.0f : ramp);
}

// ---------------------------------------------------------------------------
// Init: bcursor, sentinel, and W1/W2 -> MFMA fragment tables (hi/lo bf16).
// Slot i = ((layer*2+hl)*8 + t*4+n)*64 + lane ; 8 bf16 packed in uint4.
// frag value = W[t*32 + (lane>>4)*8 + e][n*16 + (lane&15)]
// ---------------------------------------------------------------------------
__global__ __launch_bounds__(256) void init_kernel(int* __restrict__ bcursor,
                                                   int* __restrict__ offs,
                                                   const float* __restrict__ W1,
                                                   const float* __restrict__ W2,
                                                   uint4* __restrict__ wfrag) {
    int i = blockIdx.x * 256 + threadIdx.x;
    if (i < NBUCK) bcursor[i] = i * CAP;
    if (i == 0) offs[N_NODES] = N_EDGES;
    if (i < 2048) {
        int lane  = i & 63;
        int tile  = (i >> 6) & 7;     // t*4+n
        int hl    = (i >> 9) & 1;
        int layer = (i >> 10) & 1;
        const float* W = layer ? W2 : W1;
        int kbase = (tile >> 2) * 32 + (lane >> 4) * 8;
        int j     = (tile & 3) * 16 + (lane & 15);
        unsigned p[4];
        #pragma unroll
        for (int e = 0; e < 8; e += 2) {
            float x0 = W[(kbase + e) * 64 + j];
            float x1 = W[(kbase + e + 1) * 64 + j];
            unsigned short u0, u1;
            if (hl == 0) {
                u0 = bf16_rne(x0);
                u1 = bf16_rne(x1);
            } else {
                unsigned short h0 = bf16_rne(x0);
                unsigned short h1 = bf16_rne(x1);
                u0 = bf16_rne(x0 - __uint_as_float((unsigned)h0 << 16));
                u1 = bf16_rne(x1 - __uint_as_float((unsigned)h1 << 16));
            }
            p[e >> 1] = (unsigned)u0 | ((unsigned)u1 << 16);
        }
        wfrag[i] = make_uint4(p[0], p[1], p[2], p[3]);
    }
}

// ---------------------------------------------------------------------------
// Partition into padded bucket staging (d_out). Block-chunked reservation.
// Record: {src | (dst_local<<17),  (log2fc_f16 << 16) | d_unorm16}
// ---------------------------------------------------------------------------
__global__ __launch_bounds__(1024) void partition_kernel(const int* __restrict__ dst,
                                                         const int* __restrict__ src,
                                                         const float* __restrict__ dist,
                                                         int* __restrict__ bcursor,
                                                         int2* __restrict__ brec) {
    __shared__ int hist[NBUCK];
    __shared__ int base_[NBUCK];
    int tid = threadIdx.x;
    for (int i = tid; i < NBUCK; i += 1024) hist[i] = 0;
    __syncthreads();

    int e0 = blockIdx.x * PCHUNK;
    int e1 = min(e0 + PCHUNK, N_EDGES);

    for (int t = e0 + tid; t < e1; t += 1024)
        atomicAdd(&hist[dst[t] >> BSHIFT], 1);
    __syncthreads();

    for (int i = tid; i < NBUCK; i += 1024) {
        int hv = hist[i];
        if (hv) base_[i] = atomicAdd(&bcursor[i], hv);
        hist[i] = 0;      // reuse as local cursor
    }
    __syncthreads();

    for (int t = e0 + tid; t < e1; t += 1024) {
        int d  = dst[t];
        int b  = d >> BSHIFT;
        int r  = atomicAdd(&hist[b], 1);
        float dv = dist[t];
        float fc = cutoff_fc(dv);
        float lfc = (fc > 0.0f) ? __log2f(fc) : -512.0f;
        unsigned dq = (unsigned)(fminf(fmaxf(dv, 0.0f), 1.0f) * 65535.0f + 0.5f);
        unsigned hf = (unsigned)__half_as_ushort(__float2half(lfc));
        int2 rec;
        rec.x = src[t] | ((d & (NPB - 1)) << 17);
        rec.y = (int)((hf << 16) | dq);
        brec[(size_t)base_[b] + r] = rec;
    }
}

// ---------------------------------------------------------------------------
// Compact scan: cnt[b] = bcursor[b]-b*CAP; boffs = exclusive scan.
// ---------------------------------------------------------------------------
__global__ __launch_bounds__(1024) void bscan_kernel(const int* __restrict__ bcursor,
                                                     int* __restrict__ boffs) {
    __shared__ int lds[1024];
    int tid = threadIdx.x;
    int v = (tid < NBUCK) ? (bcursor[tid] - tid * CAP) : 0;
    lds[tid] = v;
    __syncthreads();
    for (int off = 1; off < 1024; off <<= 1) {
        int x = (tid >= off) ? lds[tid - off] : 0;
        __syncthreads();
        lds[tid] += x;
        __syncthreads();
    }
    if (tid < NBUCK) boffs[tid] = lds[tid] - v;
    if (tid == 0) boffs[NBUCK] = N_EDGES;
}

// ---------------------------------------------------------------------------
// Node-sort: one block per bucket -> compact per-node CSR (rec_sorted, offs).
// ---------------------------------------------------------------------------
__global__ __launch_bounds__(256) void node_sort_kernel(const int2* __restrict__ brec,
                                                        const int* __restrict__ boffs,
                                                        int2* __restrict__ rec_sorted,
                                                        int* __restrict__ offs) {
    __shared__ int cntL[NPB];
    __shared__ int scanL[NPB];
    __shared__ int curL[NPB];

    int b   = blockIdx.x;
    int tid = threadIdx.x;
    int beg = boffs[b];
    int cnt = boffs[b + 1] - beg;
    size_t pbase = (size_t)b * CAP;
    int node0 = b << BSHIFT;

    for (int i = tid; i < NPB; i += 256) cntL[i] = 0;
    __syncthreads();

    for (int t = tid; t < cnt; t += 256)
        atomicAdd(&cntL[(brec[pbase + t].x >> 17) & (NPB - 1)], 1);
    __syncthreads();

    if (tid < NPB) scanL[tid] = cntL[tid];
    __syncthreads();
    for (int off = 1; off < NPB; off <<= 1) {
        int x = 0;
        if (tid < NPB && tid >= off) x = scanL[tid - off];
        __syncthreads();
        if (tid < NPB) scanL[tid] += x;
        __syncthreads();
    }
    if (tid < NPB) {
        int excl = scanL[tid] - cntL[tid];
        curL[tid] = excl;
        int node = node0 + tid;
        if (node < N_NODES) offs[node] = beg + excl;
    }
    __syncthreads();

    for (int t = tid; t < cnt; t += 256) {
        int2 r = brec[pbase + t];
        int dl = (r.x >> 17) & (NPB - 1);
        int p  = atomicAdd(&curL[dl], 1);
        rec_sorted[(size_t)beg + p] = r;
    }
}

// ---------------------------------------------------------------------------
// Aggregation: one wave per node, lane k owns feature k.
// Scalar record path (uniform addr -> s_load), coef = exp2(lfc - t^2).
// ---------------------------------------------------------------------------
__global__ __launch_bounds__(256) void agg_kernel(
    const float* __restrict__ h,
    const int* __restrict__ offs,
    const int2* __restrict__ rec_sorted,
    float* __restrict__ out)
{
    int w    = threadIdx.x >> 6;
    int lane = threadIdx.x & 63;
    int node = blockIdx.x * 4 + w;
    if (node >= N_NODES) return;

    int beg = __builtin_amdgcn_readfirstlane(offs[node]);
    int end = __builtin_amdgcn_readfirstlane(offs[node + 1]);
    float muK = (float)lane * (KSCALE / 63.0f);
    float acc0 = 0.0f, acc1 = 0.0f;

#define REC(J, ACC) { \
        int2 r_ = rec_sorted[(size_t)(J)]; \
        int rx_ = __builtin_amdgcn_readfirstlane(r_.x); \
        unsigned ry_ = (unsigned)__builtin_amdgcn_readfirstlane(r_.y); \
        float hv_ = h[((size_t)(rx_ & 0x1FFFF) << 6) + lane]; \
        float dqf_ = (float)(ry_ & 0xFFFFu); \
        float lfc_ = __half2float(__ushort_as_half((unsigned short)(ry_ >> 16))); \
        float t_  = fmaf(dqf_, (KSCALE / 65535.0f), -muK); \
        float a_  = fmaf(-t_, t_, lfc_); \
        ACC = fmaf(hv_, exp2f(a_), ACC); }

    int i = beg;
    int main_end = beg + ((end - beg) & ~7);
    for (; i < main_end; i += 8) {
        REC(i + 0, acc0) REC(i + 1, acc1) REC(i + 2, acc0) REC(i + 3, acc1)
        REC(i + 4, acc0) REC(i + 5, acc1) REC(i + 6, acc0) REC(i + 7, acc1)
    }
    for (; i < end; ++i) { REC(i, acc0) }
#undef REC

    out[(size_t)node * 64 + lane] = acc0 + acc1;
}

// ---------------------------------------------------------------------------
// MLP v6 — MFMA. Per wave: 16 nodes. Split-bf16 3-pass (Ah*Bh+Ah*Bl+Al*Bh)
// recovers fp32 precision. A frag: lane=(row l&15, k (l>>4)*8+i); D frag:
// col=l&15, row=(l>>4)*4+r (m89-verified). Inter-layer transpose via
// per-wave LDS tile; __threadfence_block stops alias-based hoist.
// ---------------------------------------------------------------------------
__global__ __launch_bounds__(256) void mlp_kernel(
    float* __restrict__ io, const uint4* __restrict__ wfrag,
    const float* __restrict__ b1, const float* __restrict__ b2)
{
    __shared__ float hidL[4][16][68];

    int tid  = threadIdx.x;
    int lane = tid & 63;
    int wv   = tid >> 6;
    int grp  = blockIdx.x * 4 + wv;
    if (grp >= NGRP) return;
    int node0 = grp * 16;
    int lrow = lane & 15, lk = lane >> 4;

    // ---- load A rows (agg), build bf16 hi/lo fragments
    const float* arow = io + (size_t)(node0 + lrow) * 64 + lk * 8;
    float4 t0 = *(const float4*)(arow);
    float4 t1 = *(const float4*)(arow + 4);
    float4 t2 = *(const float4*)(arow + 32);
    float4 t3 = *(const float4*)(arow + 36);
    short8_t Ah0, Al0, Ah1, Al1;
    split8(t0, t1, &Ah0, &Al0);
    split8(t2, t3, &Ah1, &Al1);

    // ---- layer 1: acc[n] = b1 + A @ W1[:, n-tile]
    f32x4_t acc[4];
    #pragma unroll
    for (int n = 0; n < 4; ++n) {
        float b = b1[n * 16 + lrow];
        acc[n] = (f32x4_t){b, b, b, b};
    }
    #pragma unroll
    for (int n = 0; n < 4; ++n) {
        short8_t wh0 = u4_to_s8(wfrag[(n) * 64 + lane]);
        short8_t wh1 = u4_to_s8(wfrag[(4 + n) * 64 + lane]);
        short8_t wl0 = u4_to_s8(wfrag[512 + n * 64 + lane]);
        short8_t wl1 = u4_to_s8(wfrag[512 + (4 + n) * 64 + lane]);
        f32x4_t c = acc[n];
        c = MFMA16(Ah0, wh0, c);
        c = MFMA16(Ah1, wh1, c);
        c = MFMA16(Ah0, wl0, c);
        c = MFMA16(Ah1, wl1, c);
        c = MFMA16(Al0, wh0, c);
        c = MFMA16(Al1, wh1, c);
        acc[n] = c;
    }

    // ---- softplus, publish hid tile [m][j] to LDS
    #pragma unroll
    for (int n = 0; n < 4; ++n) {
        #pragma unroll
        for (int r = 0; r < 4; ++r) {
            float v = acc[n][r];
            float e = exp2f(v * 1.44269504089f);
            float sp = 0.69314718056f * __log2f(1.0f + e);
            v = (v > 20.0f) ? v : sp;
            hidL[wv][lk * 4 + r][n * 16 + lrow] = v;
        }
    }
    __threadfence_block();

    // ---- read hid as layer-2 A fragments
    const float* hrow = &hidL[wv][lrow][lk * 8];
    float4 h0 = *(const float4*)(hrow);
    float4 h1 = *(const float4*)(hrow + 4);
    float4 h2 = *(const float4*)(hrow + 32);
    float4 h3 = *(const float4*)(hrow + 36);
    short8_t Bh0, Bl0, Bh1, Bl1;
    split8(h0, h1, &Bh0, &Bl0);
    split8(h2, h3, &Bh1, &Bl1);

    // ---- layer 2: out[n] = b2 + hid @ W2[:, n-tile]
    f32x4_t oac[4];
    #pragma unroll
    for (int n = 0; n < 4; ++n) {
        float b = b2[n * 16 + lrow];
        oac[n] = (f32x4_t){b, b, b, b};
    }
    #pragma unroll
    for (int n = 0; n < 4; ++n) {
        short8_t wh0 = u4_to_s8(wfrag[1024 + n * 64 + lane]);
        short8_t wh1 = u4_to_s8(wfrag[1024 + (4 + n) * 64 + lane]);
        short8_t wl0 = u4_to_s8(wfrag[1536 + n * 64 + lane]);
        short8_t wl1 = u4_to_s8(wfrag[1536 + (4 + n) * 64 + lane]);
        f32x4_t c = oac[n];
        c = MFMA16(Bh0, wh0, c);
        c = MFMA16(Bh1, wh1, c);
        c = MFMA16(Bh0, wl0, c);
        c = MFMA16(Bh1, wl1, c);
        c = MFMA16(Bl0, wh0, c);
        c = MFMA16(Bl1, wh1, c);
        oac[n] = c;
    }

    // ---- store: each (n,r) instr writes 4 full 64B lines
    #pragma unroll
    for (int n = 0; n < 4; ++n) {
        #pragma unroll
        for (int r = 0; r < 4; ++r) {
            io[(size_t)(node0 + lk * 4 + r) * 64 + n * 16 + lrow] = oac[n][r];
        }
    }
}

// ---------------------------------------------------------------------------
// Fallback (ws too small): atomic scatter-add path + simple MLP.
// ---------------------------------------------------------------------------
__global__ __launch_bounds__(256) void schnet_edge_kernel(
    const float* __restrict__ h,
    const float* __restrict__ dist,
    const int* __restrict__ src_idx,
    const int* __restrict__ dst_idx,
    float* __restrict__ agg)
{
    long long idx = (long long)blockIdx.x * 256 + threadIdx.x;
    int e = (int)(idx >> 6);
    if (e >= N_EDGES) return;
    int k = (int)(idx & 63);
    float d = dist[e];
    float c = edge_coef(d, (float)k * (1.0f / 63.0f));
    int s  = src_idx[e];
    int dn = dst_idx[e];
    atomicAdd(&agg[(long long)dn * 64 + k], h[(long long)s * 64 + k] * c);
}

__global__ __launch_bounds__(256) void mlp_fallback_kernel(
    float* __restrict__ io,
    const float* __restrict__ W1, const float* __restrict__ b1,
    const float* __restrict__ W2, const float* __restrict__ b2)
{
    __shared__ float sW1[64 * 64];
    __shared__ float sW2[64 * 64];
    __shared__ float sRow[4][64];
    __shared__ float sHid[4][64];
    int tid = threadIdx.x;
    for (int i = tid; i < 4096; i += 256) { sW1[i] = W1[i]; sW2[i] = W2[i]; }
    __syncthreads();
    int lane = tid & 63, w = tid >> 6;
    float bb1 = b1[lane], bb2 = b2[lane];
    for (int base = blockIdx.x * 4; base < N_NODES; base += gridDim.x * 4) {
        int node = base + w;
        if (node < N_NODES) sRow[w][lane] = io[(size_t)node * 64 + lane];
        __syncthreads();
        float a = bb1;
        #pragma unroll
        for (int k = 0; k < 64; ++k) a = fmaf(sRow[w][k], sW1[k * 64 + lane], a);
        sHid[w][lane] = (a > 20.f) ? a : log1pf(__expf(a));
        __syncthreads();
        float c = bb2;
        #pragma unroll
        for (int k = 0; k < 64; ++k) c = fmaf(sHid[w][k], sW2[k * 64 + lane], c);
        if (node < N_NODES) io[(size_t)node * 64 + lane] = c;
        __syncthreads();
    }
}

extern "C" void kernel_launch(void* const* d_in, const int* in_sizes, int n_in,
                              void* d_out, int out_size, void* d_ws, size_t ws_size,
                              hipStream_t stream) {
    const float* h    = (const float*)d_in[0];
    const float* dist = (const float*)d_in[1];
    const float* W1   = (const float*)d_in[2];
    const float* b1   = (const float*)d_in[3];
    const float* W2   = (const float*)d_in[4];
    const float* b2   = (const float*)d_in[5];
    const int* src    = (const int*)d_in[6];
    const int* dst    = (const int*)d_in[7];
    float* out        = (float*)d_out;

    // ws layout (ints): rec_sorted[2E] | boffs[NBUCK+1] | bcursor[NBUCK] |
    //                   offs[N+1] | wfrag[8192 uints = 32KB]
    size_t needed = ((size_t)2 * N_EDGES + NBUCK + 1 + NBUCK + N_NODES + 1 + 8192)
                    * sizeof(int);

    if (ws_size >= needed) {
        int2* rec_sorted = (int2*)d_ws;
        int* boffs       = (int*)d_ws + (size_t)2 * N_EDGES;   // NBUCK+1
        int* bcursor     = boffs + NBUCK + 1;
        int* offs        = bcursor + NBUCK;                    // N+1
        uint4* wfrag     = (uint4*)(offs + N_NODES + 1);       // 2048 uint4

        // padded bucket staging in d_out (782*4088 recs = 25.57MB <= 25.6MB)
        int2* brec = (int2*)d_out;

        init_kernel<<<16, 256, 0, stream>>>(bcursor, offs, W1, W2, wfrag);
        partition_kernel<<<PGRID, 1024, 0, stream>>>(dst, src, dist, bcursor, brec);
        bscan_kernel<<<1, 1024, 0, stream>>>(bcursor, boffs);
        node_sort_kernel<<<NBUCK, 256, 0, stream>>>(brec, boffs, rec_sorted, offs);
        agg_kernel<<<N_NODES / 4, 256, 0, stream>>>(h, offs, rec_sorted, out);
        mlp_kernel<<<(NGRP + 3) / 4, 256, 0, stream>>>(out, wfrag, b1, b2);
    } else {
        hipMemsetAsync(out, 0, (size_t)N_NODES * IN_FEATS * sizeof(float), stream);
        long long total = (long long)N_EDGES * 64;
        schnet_edge_kernel<<<(int)((total + 255) / 256), 256, 0, stream>>>(
            h, dist, src, dst, out);
        mlp_fallback_kernel<<<2048, 256, 0, stream>>>(out, W1, b1, W2, b2);
    }
}